// Round 1
// baseline (1289.915 us; speedup 1.0000x reference)
//
#include <hip/hip_runtime.h>
#include <hip/hip_bf16.h>

typedef __attribute__((ext_vector_type(8))) short bf16x8;
typedef __attribute__((ext_vector_type(4))) float f32x4;
typedef __attribute__((ext_vector_type(4))) unsigned short u16x4;

#define SEQ   4096
#define DIM   1024
#define MTOT  16384

static __device__ __forceinline__ unsigned short f2bf(float f) {
  union { float f; unsigned u; } v; v.f = f;
  unsigned r = v.u + 0x7FFFu + ((v.u >> 16) & 1u);
  return (unsigned short)(r >> 16);
}

static __device__ __forceinline__ bf16x8 pack8(f32x4 a, f32x4 b) {
  bf16x8 v;
  v[0]=(short)f2bf(a[0]); v[1]=(short)f2bf(a[1]);
  v[2]=(short)f2bf(a[2]); v[3]=(short)f2bf(a[3]);
  v[4]=(short)f2bf(b[0]); v[5]=(short)f2bf(b[1]);
  v[6]=(short)f2bf(b[2]); v[7]=(short)f2bf(b[3]);
  return v;
}

// ---------------- QKV projection: C = x * W^T, bf16 out ----------------
// z=0 -> Q [m][e], z=1 -> K [m][e], z=2 -> Vt [b][e][s]
__global__ __launch_bounds__(256) void qkv_gemm(
    const float* __restrict__ x,
    const float* __restrict__ Wq,
    const float* __restrict__ Wk,
    const float* __restrict__ Wv,
    unsigned short* __restrict__ ws)
{
  const int z = blockIdx.z;
  const float* __restrict__ W = (z == 0) ? Wq : (z == 1) ? Wk : Wv;
  unsigned short* __restrict__ outb = ws + (size_t)z * ((size_t)MTOT * DIM);

  const int n0 = blockIdx.x * 64;
  const int m0 = blockIdx.y * 64;
  const int tid  = threadIdx.x;
  const int lane = tid & 63;
  const int wid  = tid >> 6;
  const int mw = wid >> 1, nw = wid & 1;
  const int l15 = lane & 15, quad = lane >> 4;

  __shared__ unsigned short Al[64 * 72];   // 64x64 bf16, stride 72 (pad)
  __shared__ unsigned short Bl[64 * 72];

  const int srow = tid >> 2;         // 0..63
  const int scol = (tid & 3) * 8;    // 0,8,16,24

  f32x4 acc[2][2] = {};

  for (int k0 = 0; k0 < DIM; k0 += 64) {
    const float* ap = x + (size_t)(m0 + srow) * DIM + k0 + scol;
    const float* bp = W + (size_t)(n0 + srow) * DIM + k0 + scol;
    f32x4 a0 = *(const f32x4*)(ap);
    f32x4 a1 = *(const f32x4*)(ap + 4);
    f32x4 a2 = *(const f32x4*)(ap + 32);
    f32x4 a3 = *(const f32x4*)(ap + 36);
    f32x4 b0 = *(const f32x4*)(bp);
    f32x4 b1 = *(const f32x4*)(bp + 4);
    f32x4 b2 = *(const f32x4*)(bp + 32);
    f32x4 b3 = *(const f32x4*)(bp + 36);
    __syncthreads();   // previous iter's fragment reads done
    *(bf16x8*)&Al[srow * 72 + scol]      = pack8(a0, a1);
    *(bf16x8*)&Al[srow * 72 + scol + 32] = pack8(a2, a3);
    *(bf16x8*)&Bl[srow * 72 + scol]      = pack8(b0, b1);
    *(bf16x8*)&Bl[srow * 72 + scol + 32] = pack8(b2, b3);
    __syncthreads();
#pragma unroll
    for (int ks = 0; ks < 2; ++ks) {
      bf16x8 af[2], bfr[2];
      af[0]  = *(const bf16x8*)&Al[(mw * 32 +  0 + l15) * 72 + ks * 32 + quad * 8];
      af[1]  = *(const bf16x8*)&Al[(mw * 32 + 16 + l15) * 72 + ks * 32 + quad * 8];
      bfr[0] = *(const bf16x8*)&Bl[(nw * 32 +  0 + l15) * 72 + ks * 32 + quad * 8];
      bfr[1] = *(const bf16x8*)&Bl[(nw * 32 + 16 + l15) * 72 + ks * 32 + quad * 8];
#pragma unroll
      for (int m = 0; m < 2; ++m)
#pragma unroll
        for (int n = 0; n < 2; ++n)
          acc[m][n] = __builtin_amdgcn_mfma_f32_16x16x32_bf16(af[m], bfr[n], acc[m][n], 0, 0, 0);
    }
  }

  // Epilogue. C/D layout: col = lane&15 (n), row = quad*4+reg (m).
  if (z < 2) {
#pragma unroll
    for (int m = 0; m < 2; ++m)
#pragma unroll
      for (int n = 0; n < 2; ++n) {
        int gm = m0 + mw * 32 + m * 16 + quad * 4;
        int ge = n0 + nw * 32 + n * 16 + l15;
        unsigned short* p = outb + (size_t)gm * DIM + ge;
#pragma unroll
        for (int r = 0; r < 4; ++r)
          p[(size_t)r * DIM] = f2bf(acc[m][n][r]);
      }
  } else {
#pragma unroll
    for (int m = 0; m < 2; ++m)
#pragma unroll
      for (int n = 0; n < 2; ++n) {
        int gm = m0 + mw * 32 + m * 16 + quad * 4;   // 4 consecutive s
        int ge = n0 + nw * 32 + n * 16 + l15;
        int bb = gm >> 12, ss = gm & 4095;
        u16x4 v4;
#pragma unroll
        for (int r = 0; r < 4; ++r) v4[r] = f2bf(acc[m][n][r]);
        *(u16x4*)(outb + ((size_t)bb * DIM + ge) * SEQ + ss) = v4;
      }
  }
}

// ---------------- Flash attention, causal, single head d=1024 ----------------
// Block: 512 threads (8 waves). Block owns 32 query rows; wave w owns d-slice
// [128w,128w+128). Per 32-key tile: partial QK^T per wave -> LDS reduce +
// online softmax (all waves) -> PV as O^T = V^T * P^T.
__global__ __launch_bounds__(512, 2) void attn(
    const unsigned short* __restrict__ Qg,
    const unsigned short* __restrict__ Kg,
    const unsigned short* __restrict__ Vtg,
    float* __restrict__ out)
{
  __shared__ float Sp[8][32][33];          // per-wave partial scores
  __shared__ unsigned short Pl[32][40];    // P tile, bf16 (padded stride)
  __shared__ float mst[32], lst[32], alf[32];

  const int bid  = blockIdx.x;
  const int tile = (bid & 1) ? (511 - (bid >> 1)) : (bid >> 1);  // work pairing
  const int b  = tile >> 7;
  const int q0 = (tile & 127) << 5;

  const int tid  = threadIdx.x;
  const int w    = tid >> 6;
  const int lane = tid & 63;
  const int l15  = lane & 15, quad = lane >> 4;

  if (tid < 32) { mst[tid] = -__builtin_inff(); lst[tid] = 0.f; }

  // Q fragments (A layout: m=lane&15, k=quad*8+j), held in registers
  bf16x8 qf[2][4];
  const size_t qbase = (size_t)(b * SEQ + q0) * DIM;
#pragma unroll
  for (int m = 0; m < 2; ++m)
#pragma unroll
    for (int ks = 0; ks < 4; ++ks)
      qf[m][ks] = *(const bf16x8*)(Qg + qbase + (size_t)(m * 16 + l15) * DIM +
                                   w * 128 + ks * 32 + quad * 8);

  f32x4 oac[8][2] = {};   // O^T slice: [d-sub 8][q-sub 2]

  const int rowl = lane >> 4;          // 0..3
  const int srow = w * 4 + rowl;       // this wave's softmax rows
  const int c0   = (lane & 15) * 2;
  const float scale = 0.03125f;        // 1/sqrt(1024)

  for (int j0 = 0; j0 <= q0; j0 += 32) {
    // ---- partial QK^T over this wave's 128-d slice ----
    f32x4 sac[2][2] = {};
#pragma unroll
    for (int ks = 0; ks < 4; ++ks) {
      const size_t koff = (size_t)(b * SEQ + j0 + l15) * DIM + w * 128 + ks * 32 + quad * 8;
      bf16x8 kf0 = *(const bf16x8*)(Kg + koff);
      bf16x8 kf1 = *(const bf16x8*)(Kg + koff + (size_t)16 * DIM);
#pragma unroll
      for (int m = 0; m < 2; ++m) {
        sac[m][0] = __builtin_amdgcn_mfma_f32_16x16x32_bf16(qf[m][ks], kf0, sac[m][0], 0, 0, 0);
        sac[m][1] = __builtin_amdgcn_mfma_f32_16x16x32_bf16(qf[m][ks], kf1, sac[m][1], 0, 0, 0);
      }
    }
#pragma unroll
    for (int m = 0; m < 2; ++m)
#pragma unroll
      for (int n = 0; n < 2; ++n)
#pragma unroll
        for (int r = 0; r < 4; ++r)
          Sp[w][m * 16 + quad * 4 + r][n * 16 + l15] = sac[m][n][r];
    __syncthreads();

    // ---- online softmax: wave w handles rows 4w..4w+3, 2 cols/lane ----
    {
      float s0 = 0.f, s1 = 0.f;
#pragma unroll
      for (int wv = 0; wv < 8; ++wv) {
        s0 += Sp[wv][srow][c0];
        s1 += Sp[wv][srow][c0 + 1];
      }
      s0 *= scale; s1 *= scale;
      const int qg = q0 + srow;
      if (j0 + c0     > qg) s0 = -__builtin_inff();
      if (j0 + c0 + 1 > qg) s1 = -__builtin_inff();
      float mx = fmaxf(s0, s1);
#pragma unroll
      for (int off = 1; off < 16; off <<= 1) mx = fmaxf(mx, __shfl_xor(mx, off, 16));
      const float mold = mst[srow];
      const float mnew = fmaxf(mold, mx);
      const float al   = __expf(mold - mnew);
      const float p0 = __expf(s0 - mnew), p1 = __expf(s1 - mnew);
      unsigned pu = ((unsigned)f2bf(p1) << 16) | (unsigned)f2bf(p0);
      *(unsigned*)&Pl[srow][c0] = pu;
      float sm = p0 + p1;
#pragma unroll
      for (int off = 1; off < 16; off <<= 1) sm += __shfl_xor(sm, off, 16);
      if ((lane & 15) == 0) {
        lst[srow] = lst[srow] * al + sm;
        mst[srow] = mnew;
        alf[srow] = al;
      }
    }
    __syncthreads();

    // ---- rescale O, then PV: O^T += V^T * P^T ----
    const float a0 = alf[l15], a1 = alf[16 + l15];
#pragma unroll
    for (int m = 0; m < 8; ++m)
#pragma unroll
      for (int r = 0; r < 4; ++r) { oac[m][0][r] *= a0; oac[m][1][r] *= a1; }

    bf16x8 pf0 = *(const bf16x8*)&Pl[l15][quad * 8];
    bf16x8 pf1 = *(const bf16x8*)&Pl[16 + l15][quad * 8];
    const unsigned short* vb = Vtg + ((size_t)b * DIM + w * 128) * SEQ + j0;
#pragma unroll
    for (int m = 0; m < 8; ++m) {
      bf16x8 vf = *(const bf16x8*)(vb + (size_t)(m * 16 + l15) * SEQ + quad * 8);
      oac[m][0] = __builtin_amdgcn_mfma_f32_16x16x32_bf16(vf, pf0, oac[m][0], 0, 0, 0);
      oac[m][1] = __builtin_amdgcn_mfma_f32_16x16x32_bf16(vf, pf1, oac[m][1], 0, 0, 0);
    }
    // no barrier needed: next iter's LDS writes are fenced by its own barriers
  }

  // ---- epilogue: O = O^T / l, scattered float4 stores ----
  const float inv0 = 1.f / lst[l15];
  const float inv1 = 1.f / lst[16 + l15];
#pragma unroll
  for (int m = 0; m < 8; ++m)
#pragma unroll
    for (int n = 0; n < 2; ++n) {
      const float inv = n ? inv1 : inv0;
      const int qg = q0 + n * 16 + l15;
      const int d  = w * 128 + m * 16 + quad * 4;
      f32x4 v;
#pragma unroll
      for (int r = 0; r < 4; ++r) v[r] = oac[m][n][r] * inv;
      *(f32x4*)(out + (size_t)(b * SEQ + qg) * DIM + d) = v;
    }
}

extern "C" void kernel_launch(void* const* d_in, const int* in_sizes, int n_in,
                              void* d_out, int out_size, void* d_ws, size_t ws_size,
                              hipStream_t stream) {
  const float* x  = (const float*)d_in[0];
  const float* Wq = (const float*)d_in[1];
  const float* Wk = (const float*)d_in[2];
  const float* Wv = (const float*)d_in[3];
  unsigned short* ws = (unsigned short*)d_ws;   // Q | K | Vt, bf16, 32MB each
  float* out = (float*)d_out;

  dim3 g1(DIM / 64, MTOT / 64, 3);
  qkv_gemm<<<g1, 256, 0, stream>>>(x, Wq, Wk, Wv, ws);

  const size_t n = (size_t)MTOT * DIM;
  attn<<<dim3(512), 512, 0, stream>>>(ws, ws + n, ws + 2 * n, out);
}

// Round 2
// 1098.264 us; speedup vs baseline: 1.1745x; 1.1745x over previous
//
#include <hip/hip_runtime.h>
#include <hip/hip_bf16.h>

typedef __attribute__((ext_vector_type(8))) short bf16x8;
typedef __attribute__((ext_vector_type(4))) float f32x4;
typedef __attribute__((ext_vector_type(4))) unsigned short u16x4;

#define SEQ   4096
#define DIM   1024
#define MTOT  16384

static __device__ __forceinline__ unsigned short f2bf(float f) {
  union { float f; unsigned u; } v; v.f = f;
  unsigned r = v.u + 0x7FFFu + ((v.u >> 16) & 1u);
  return (unsigned short)(r >> 16);
}

static __device__ __forceinline__ bf16x8 pack8(f32x4 a, f32x4 b) {
  bf16x8 v;
  v[0]=(short)f2bf(a[0]); v[1]=(short)f2bf(a[1]);
  v[2]=(short)f2bf(a[2]); v[3]=(short)f2bf(a[3]);
  v[4]=(short)f2bf(b[0]); v[5]=(short)f2bf(b[1]);
  v[6]=(short)f2bf(b[2]); v[7]=(short)f2bf(b[3]);
  return v;
}

// LDS-only barrier: waits lgkmcnt(0) but leaves global loads (vmcnt) in
// flight across the barrier — avoids the compiler's vmcnt(0) drain that
// __syncthreads() forces (the ~20% stall per the m97 analysis).
// 0xC07F = vmcnt=63 (bits 3:0 + 15:14), expcnt=7, lgkmcnt=0.
static __device__ __forceinline__ void barrier_lds() {
  asm volatile("" ::: "memory");
  __builtin_amdgcn_s_waitcnt(0xC07F);
  __builtin_amdgcn_s_barrier();
  asm volatile("" ::: "memory");
}

// ---------------- QKV projection: C = x * W^T, bf16 out ----------------
// z=0 -> Q [m][e] (pre-scaled by 1/sqrt(D)), z=1 -> K [m][e], z=2 -> Vt [b][e][s]
__global__ __launch_bounds__(256) void qkv_gemm(
    const float* __restrict__ x,
    const float* __restrict__ Wq,
    const float* __restrict__ Wk,
    const float* __restrict__ Wv,
    unsigned short* __restrict__ ws)
{
  const int z = blockIdx.z;
  const float* __restrict__ W = (z == 0) ? Wq : (z == 1) ? Wk : Wv;
  unsigned short* __restrict__ outb = ws + (size_t)z * ((size_t)MTOT * DIM);

  const int n0 = blockIdx.x * 64;
  const int m0 = blockIdx.y * 64;
  const int tid  = threadIdx.x;
  const int lane = tid & 63;
  const int wid  = tid >> 6;
  const int mw = wid >> 1, nw = wid & 1;
  const int l15 = lane & 15, quad = lane >> 4;

  __shared__ unsigned short Al[64 * 72];
  __shared__ unsigned short Bl[64 * 72];

  const int srow = tid >> 2;
  const int scol = (tid & 3) * 8;

  f32x4 acc[2][2] = {};

  for (int k0 = 0; k0 < DIM; k0 += 64) {
    const float* ap = x + (size_t)(m0 + srow) * DIM + k0 + scol;
    const float* bp = W + (size_t)(n0 + srow) * DIM + k0 + scol;
    f32x4 a0 = *(const f32x4*)(ap);
    f32x4 a1 = *(const f32x4*)(ap + 4);
    f32x4 a2 = *(const f32x4*)(ap + 32);
    f32x4 a3 = *(const f32x4*)(ap + 36);
    f32x4 b0 = *(const f32x4*)(bp);
    f32x4 b1 = *(const f32x4*)(bp + 4);
    f32x4 b2 = *(const f32x4*)(bp + 32);
    f32x4 b3 = *(const f32x4*)(bp + 36);
    __syncthreads();
    *(bf16x8*)&Al[srow * 72 + scol]      = pack8(a0, a1);
    *(bf16x8*)&Al[srow * 72 + scol + 32] = pack8(a2, a3);
    *(bf16x8*)&Bl[srow * 72 + scol]      = pack8(b0, b1);
    *(bf16x8*)&Bl[srow * 72 + scol + 32] = pack8(b2, b3);
    __syncthreads();
#pragma unroll
    for (int ks = 0; ks < 2; ++ks) {
      bf16x8 af[2], bfr[2];
      af[0]  = *(const bf16x8*)&Al[(mw * 32 +  0 + l15) * 72 + ks * 32 + quad * 8];
      af[1]  = *(const bf16x8*)&Al[(mw * 32 + 16 + l15) * 72 + ks * 32 + quad * 8];
      bfr[0] = *(const bf16x8*)&Bl[(nw * 32 +  0 + l15) * 72 + ks * 32 + quad * 8];
      bfr[1] = *(const bf16x8*)&Bl[(nw * 32 + 16 + l15) * 72 + ks * 32 + quad * 8];
#pragma unroll
      for (int m = 0; m < 2; ++m)
#pragma unroll
        for (int n = 0; n < 2; ++n)
          acc[m][n] = __builtin_amdgcn_mfma_f32_16x16x32_bf16(af[m], bfr[n], acc[m][n], 0, 0, 0);
    }
  }

  const float osc = (z == 0) ? 0.03125f : 1.0f;   // fold softmax scale into Q
  if (z < 2) {
#pragma unroll
    for (int m = 0; m < 2; ++m)
#pragma unroll
      for (int n = 0; n < 2; ++n) {
        int gm = m0 + mw * 32 + m * 16 + quad * 4;
        int ge = n0 + nw * 32 + n * 16 + l15;
        unsigned short* p = outb + (size_t)gm * DIM + ge;
#pragma unroll
        for (int r = 0; r < 4; ++r)
          p[(size_t)r * DIM] = f2bf(acc[m][n][r] * osc);
      }
  } else {
#pragma unroll
    for (int m = 0; m < 2; ++m)
#pragma unroll
      for (int n = 0; n < 2; ++n) {
        int gm = m0 + mw * 32 + m * 16 + quad * 4;
        int ge = n0 + nw * 32 + n * 16 + l15;
        int bb = gm >> 12, ss = gm & 4095;
        u16x4 v4;
#pragma unroll
        for (int r = 0; r < 4; ++r) v4[r] = f2bf(acc[m][n][r]);
        *(u16x4*)(outb + ((size_t)bb * DIM + ge) * SEQ + ss) = v4;
      }
  }
}

// ---------------- Flash attention v2: dual Q-tile (Bq=64), causal ----------------
// 256 blocks (1/CU) x 512 threads (8 waves). Block owns 64 query rows
// (q0 = 64*p); wave w owns d-slice [128w, 128w+128). Per 32-key tile:
// per-wave partial QK^T (full Bq) -> LDS reduce + online softmax over 64
// rows -> PV as O^T = V^T * P^T. LDS-only barriers; V prefetched across b1.
__global__ __launch_bounds__(512) void attn2(
    const unsigned short* __restrict__ Qg,
    const unsigned short* __restrict__ Kg,
    const unsigned short* __restrict__ Vtg,
    float* __restrict__ out)
{
  __shared__ float Sp[8][64][33];          // per-wave partial scores (67.6 KB)
  __shared__ unsigned short Pl[64][40];    // P tile bf16, stride 40 (16B-align rows)
  __shared__ float mst[64], lst[64], alf[64];

  const int bid = blockIdx.x;
  const int b   = bid >> 6;          // batch
  const int p   = bid & 63;          // dual-tile index
  const int q0  = p << 6;            // 64 query rows [q0, q0+64)

  const int tid  = threadIdx.x;
  const int w    = tid >> 6;
  const int lane = tid & 63;
  const int l15  = lane & 15, quad = lane >> 4;

  if (tid < 64) { mst[tid] = -__builtin_inff(); lst[tid] = 0.f; }

  // Q fragments (A layout: m=lane&15, k=quad*8+j). 16 frags = 64 VGPRs.
  bf16x8 qf[4][4];
  const size_t qbase = (size_t)(b * SEQ + q0) * DIM;
#pragma unroll
  for (int mq = 0; mq < 4; ++mq)
#pragma unroll
    for (int ks = 0; ks < 4; ++ks)
      qf[mq][ks] = *(const bf16x8*)(Qg + qbase + (size_t)(mq * 16 + l15) * DIM +
                                    w * 128 + ks * 32 + quad * 8);

  f32x4 oac[8][4] = {};   // O^T slice: [d-sub 8][q-sub 4] = 128 VGPRs

  // softmax indexing: 8 rows/wave, 8 lanes/row, 4 cols/lane
  const int srow = tid >> 3;           // 0..63
  const int c0   = (tid & 7) * 4;      // 0,4,...,28
  const int qg   = q0 + srow;

  const int jmax = q0 + 32;            // last key-tile base (covers q0+63)
  for (int j0 = 0; j0 <= jmax; j0 += 32) {
    // ---- partial QK^T over this wave's 128-d slice (Q pre-scaled) ----
    f32x4 sac[4][2] = {};
#pragma unroll
    for (int ks = 0; ks < 4; ++ks) {
      const size_t koff = (size_t)(b * SEQ + j0 + l15) * DIM + w * 128 + ks * 32 + quad * 8;
      bf16x8 kf0 = *(const bf16x8*)(Kg + koff);
      bf16x8 kf1 = *(const bf16x8*)(Kg + koff + (size_t)16 * DIM);
#pragma unroll
      for (int mq = 0; mq < 4; ++mq) {
        sac[mq][0] = __builtin_amdgcn_mfma_f32_16x16x32_bf16(qf[mq][ks], kf0, sac[mq][0], 0, 0, 0);
        sac[mq][1] = __builtin_amdgcn_mfma_f32_16x16x32_bf16(qf[mq][ks], kf1, sac[mq][1], 0, 0, 0);
      }
    }
#pragma unroll
    for (int mq = 0; mq < 4; ++mq)
#pragma unroll
      for (int n = 0; n < 2; ++n)
#pragma unroll
        for (int r = 0; r < 4; ++r)
          Sp[w][mq * 16 + quad * 4 + r][n * 16 + l15] = sac[mq][n][r];

    // ---- V prefetch: issue now, stays in flight across b1 + softmax ----
    bf16x8 vf[8];
    const unsigned short* vb = Vtg + ((size_t)b * DIM + w * 128) * SEQ + j0;
#pragma unroll
    for (int md = 0; md < 8; ++md)
      vf[md] = *(const bf16x8*)(vb + (size_t)(md * 16 + l15) * SEQ + quad * 8);

    barrier_lds();   // b1: Sp visible; vf NOT drained

    // ---- online softmax: each thread owns (srow, cols c0..c0+3) ----
    {
      float s[4];
#pragma unroll
      for (int i = 0; i < 4; ++i) {
        float acc = 0.f;
#pragma unroll
        for (int wv = 0; wv < 8; ++wv) acc += Sp[wv][srow][c0 + i];
        s[i] = (j0 + c0 + i > qg) ? -__builtin_inff() : acc;
      }
      float mx = fmaxf(fmaxf(s[0], s[1]), fmaxf(s[2], s[3]));
#pragma unroll
      for (int off = 1; off < 8; off <<= 1) mx = fmaxf(mx, __shfl_xor(mx, off, 8));
      const float mold = mst[srow];
      const float mnew = fmaxf(mold, mx);
      const float al   = __expf(mold - mnew);
      float pv[4];
#pragma unroll
      for (int i = 0; i < 4; ++i) pv[i] = __expf(s[i] - mnew);
      u16x4 pb;
#pragma unroll
      for (int i = 0; i < 4; ++i) pb[i] = f2bf(pv[i]);
      *(u16x4*)&Pl[srow][c0] = pb;
      float sm = (pv[0] + pv[1]) + (pv[2] + pv[3]);
#pragma unroll
      for (int off = 1; off < 8; off <<= 1) sm += __shfl_xor(sm, off, 8);
      if ((tid & 7) == 0) {
        lst[srow] = lst[srow] * al + sm;
        mst[srow] = mnew;
        alf[srow] = al;
      }
    }
    barrier_lds();   // b2: Pl/alf visible; vf still free-flying

    // ---- rescale O only when some alpha < 1 (max update is rare) ----
    const float a0 = alf[l15], a1 = alf[16 + l15], a2 = alf[32 + l15], a3 = alf[48 + l15];
    if (__ballot((a0 != 1.f) | (a1 != 1.f) | (a2 != 1.f) | (a3 != 1.f))) {
#pragma unroll
      for (int md = 0; md < 8; ++md)
#pragma unroll
        for (int r = 0; r < 4; ++r) {
          oac[md][0][r] *= a0; oac[md][1][r] *= a1;
          oac[md][2][r] *= a2; oac[md][3][r] *= a3;
        }
    }

    // ---- PV: O^T += V^T * P^T ----
    bf16x8 pf[4];
#pragma unroll
    for (int nq = 0; nq < 4; ++nq)
      pf[nq] = *(const bf16x8*)&Pl[nq * 16 + l15][quad * 8];
#pragma unroll
    for (int md = 0; md < 8; ++md)
#pragma unroll
      for (int nq = 0; nq < 4; ++nq)
        oac[md][nq] = __builtin_amdgcn_mfma_f32_16x16x32_bf16(vf[md], pf[nq], oac[md][nq], 0, 0, 0);
    // next iter's Sp writes are fenced by its own b1 (Pl rewritten after next b1's
    // softmax — wait: Pl written in softmax after b1, read here before next b1's
    // softmax... ordering: PV reads Pl, then loop -> QK -> Sp stores -> b1 ->
    // softmax writes Pl. PV's Pl reads complete before this wave reaches next b1,
    // and other waves' Pl writes happen only after that b1. Safe.
  }

  // ---- epilogue: O = O^T / l ----
  const float inv[4] = { 1.f / lst[l15], 1.f / lst[16 + l15],
                         1.f / lst[32 + l15], 1.f / lst[48 + l15] };
#pragma unroll
  for (int md = 0; md < 8; ++md)
#pragma unroll
    for (int nq = 0; nq < 4; ++nq) {
      const int qq = q0 + nq * 16 + l15;
      const int d  = w * 128 + md * 16 + quad * 4;
      f32x4 v;
#pragma unroll
      for (int r = 0; r < 4; ++r) v[r] = oac[md][nq][r] * inv[nq];
      *(f32x4*)(out + (size_t)(b * SEQ + qq) * DIM + d) = v;
    }
}

extern "C" void kernel_launch(void* const* d_in, const int* in_sizes, int n_in,
                              void* d_out, int out_size, void* d_ws, size_t ws_size,
                              hipStream_t stream) {
  const float* x  = (const float*)d_in[0];
  const float* Wq = (const float*)d_in[1];
  const float* Wk = (const float*)d_in[2];
  const float* Wv = (const float*)d_in[3];
  unsigned short* ws = (unsigned short*)d_ws;   // Q | K | Vt, bf16, 32MB each
  float* out = (float*)d_out;

  dim3 g1(DIM / 64, MTOT / 64, 3);
  qkv_gemm<<<g1, 256, 0, stream>>>(x, Wq, Wk, Wv, ws);

  const size_t n = (size_t)MTOT * DIM;
  attn2<<<dim3(256), 512, 0, stream>>>(ws, ws + n, ws + 2 * n, out);
}

// Round 3
// 721.006 us; speedup vs baseline: 1.7890x; 1.5232x over previous
//
#include <hip/hip_runtime.h>
#include <hip/hip_bf16.h>

typedef __attribute__((ext_vector_type(8))) short bf16x8;
typedef __attribute__((ext_vector_type(4))) float f32x4;
typedef __attribute__((ext_vector_type(4))) unsigned short u16x4;

#define SEQ   4096
#define DIM   1024
#define MTOT  16384

static __device__ __forceinline__ unsigned short f2bf(float f) {
  union { float f; unsigned u; } v; v.f = f;
  unsigned r = v.u + 0x7FFFu + ((v.u >> 16) & 1u);
  return (unsigned short)(r >> 16);
}

static __device__ __forceinline__ bf16x8 pack8(f32x4 a, f32x4 b) {
  bf16x8 v;
  v[0]=(short)f2bf(a[0]); v[1]=(short)f2bf(a[1]);
  v[2]=(short)f2bf(a[2]); v[3]=(short)f2bf(a[3]);
  v[4]=(short)f2bf(b[0]); v[5]=(short)f2bf(b[1]);
  v[6]=(short)f2bf(b[2]); v[7]=(short)f2bf(b[3]);
  return v;
}

// LDS-only barrier: lgkmcnt(0) + s_barrier, leaves vmcnt in flight.
// 0xC07F = vmcnt=63, expcnt=7, lgkmcnt=0 (gfx9 encoding).
static __device__ __forceinline__ void barrier_lds() {
  asm volatile("" ::: "memory");
  __builtin_amdgcn_s_waitcnt(0xC07F);
  __builtin_amdgcn_s_barrier();
  asm volatile("" ::: "memory");
}

// ---------------- fp32 -> bf16 preconvert (optionally scaled) ----------------
__global__ __launch_bounds__(256) void conv_bf16(
    const float* __restrict__ src, unsigned short* __restrict__ dst,
    int n8, float scale)
{
  const int i = blockIdx.x * 256 + threadIdx.x;
  if (i < n8) {
    const f32x4* s = (const f32x4*)(src + (size_t)i * 8);
    f32x4 a = s[0], b = s[1];
#pragma unroll
    for (int r = 0; r < 4; ++r) { a[r] *= scale; b[r] *= scale; }
    *(bf16x8*)(dst + (size_t)i * 8) = pack8(a, b);
  }
}

// ---------------- QKV GEMM, m97-style: 128x128 tile, global_load_lds w16 ----
// C = xb * Wz^T (both row-major over k). z=0 -> Q (Wq pre-scaled), z=1 -> K,
// z=2 -> Vt [b][e][s].
__global__ __launch_bounds__(256) void qkv_gemm2(
    const unsigned short* __restrict__ xb,
    const unsigned short* __restrict__ Wb,    // Wq|Wk|Wv bf16
    unsigned short* __restrict__ outQ)        // Q | K | Vt contiguous
{
  const int z = blockIdx.z;
  const unsigned short* __restrict__ Wz = Wb + (size_t)z * (DIM * DIM);
  unsigned short* __restrict__ outb = outQ + (size_t)z * ((size_t)MTOT * DIM);

  const int n0 = blockIdx.x * 128;
  const int m0 = blockIdx.y * 128;
  const int tid = threadIdx.x, ln = tid & 63, wv = tid >> 6;
  const int l15 = ln & 15, quad = ln >> 4;
  const int mw = wv >> 1, nw = wv & 1;
  const int lrow = ln >> 3, lcol = (ln & 7) * 8;

  __shared__ unsigned short Al[128 * 64];   // no padding: global_load_lds layout
  __shared__ unsigned short Bl[128 * 64];

  f32x4 acc[4][4] = {};

  for (int k0 = 0; k0 < DIM; k0 += 64) {
    __syncthreads();   // prior fragment reads done before DMA overwrites LDS
#pragma unroll
    for (int r = 0; r < 4; ++r) {
      const int rr = (wv * 4 + r) * 8 + lrow;
      const unsigned short* ga = xb + (size_t)(m0 + rr) * DIM + k0 + lcol;
      const unsigned short* gb = Wz + (size_t)(n0 + rr) * DIM + k0 + lcol;
      __builtin_amdgcn_global_load_lds(
          (const __attribute__((address_space(1))) void*)ga,
          (__attribute__((address_space(3))) void*)&Al[(wv * 4 + r) * 512], 16, 0, 0);
      __builtin_amdgcn_global_load_lds(
          (const __attribute__((address_space(1))) void*)gb,
          (__attribute__((address_space(3))) void*)&Bl[(wv * 4 + r) * 512], 16, 0, 0);
    }
    __syncthreads();   // vmcnt(0) drain: DMA complete, LDS valid
#pragma unroll
    for (int ks = 0; ks < 2; ++ks) {
      bf16x8 af[4], bfr[4];
#pragma unroll
      for (int i = 0; i < 4; ++i) {
        af[i]  = *(const bf16x8*)&Al[(mw * 64 + i * 16 + l15) * 64 + ks * 32 + quad * 8];
        bfr[i] = *(const bf16x8*)&Bl[(nw * 64 + i * 16 + l15) * 64 + ks * 32 + quad * 8];
      }
#pragma unroll
      for (int mi = 0; mi < 4; ++mi)
#pragma unroll
        for (int ni = 0; ni < 4; ++ni)
          acc[mi][ni] = __builtin_amdgcn_mfma_f32_16x16x32_bf16(af[mi], bfr[ni], acc[mi][ni], 0, 0, 0);
    }
  }

  if (z < 2) {
#pragma unroll
    for (int mi = 0; mi < 4; ++mi)
#pragma unroll
      for (int ni = 0; ni < 4; ++ni) {
        const int m = m0 + mw * 64 + mi * 16 + quad * 4;
        const int e = n0 + nw * 64 + ni * 16 + l15;
        unsigned short* p = outb + (size_t)m * DIM + e;
#pragma unroll
        for (int r = 0; r < 4; ++r) p[(size_t)r * DIM] = f2bf(acc[mi][ni][r]);
      }
  } else {
#pragma unroll
    for (int mi = 0; mi < 4; ++mi)
#pragma unroll
      for (int ni = 0; ni < 4; ++ni) {
        const int m = m0 + mw * 64 + mi * 16 + quad * 4;   // s index (4 consec)
        const int e = n0 + nw * 64 + ni * 16 + l15;
        const int bb = m >> 12, ss = m & 4095;
        u16x4 v4;
#pragma unroll
        for (int r = 0; r < 4; ++r) v4[r] = f2bf(acc[mi][ni][r]);
        *(u16x4*)(outb + ((size_t)bb * DIM + e) * SEQ + ss) = v4;
      }
  }
}

// ---------------- Flash attention v3: split-K halves + XCD-aware mapping ----
// 512 blocks x 512 threads. bid -> (b, P, h): XCD x=bid&7 hosts batch x>>1,
// tiles P = 2t+(x&1); j<32 -> h=0 (keys [0,32(P+1))), j>=32 -> h=1
// (keys [32(P+1), 64(P+1))). CU c pairs tiles t=c and t=31-c -> balanced.
// h=0 writes unnormalized f32 partial to `outp` (d_out), h=1 writes bf16
// partial to O1; both write m,l to St. Combine kernel merges.
__global__ __launch_bounds__(512) void attn3(
    const unsigned short* __restrict__ Qg,
    const unsigned short* __restrict__ Kg,
    const unsigned short* __restrict__ Vtg,
    float* __restrict__ outp,
    unsigned short* __restrict__ O1,
    float* __restrict__ St)
{
  __shared__ float Sp[8][64][33];
  __shared__ unsigned short Pl[64][40];
  __shared__ float mst[64], lst[64], alf[64];

  const int bid = blockIdx.x;
  const int x = bid & 7, j = bid >> 3;
  const int b = x >> 1, o = x & 1;
  const int h = (j >= 32) ? 1 : 0;
  const int t = h ? (63 - j) : j;
  const int P = 2 * t + o;
  const int q0 = P << 6;
  const int nhalf = P + 1;
  const int jbase = h ? 32 * (P + 1) : 0;

  const int tid  = threadIdx.x;
  const int w    = tid >> 6;
  const int lane = tid & 63;
  const int l15  = lane & 15, quad = lane >> 4;

  if (tid < 64) { mst[tid] = -1e30f; lst[tid] = 0.f; }   // finite sentinel

  bf16x8 qf[4][4];
  const size_t qbase = (size_t)(b * SEQ + q0) * DIM;
#pragma unroll
  for (int mq = 0; mq < 4; ++mq)
#pragma unroll
    for (int ks = 0; ks < 4; ++ks)
      qf[mq][ks] = *(const bf16x8*)(Qg + qbase + (size_t)(mq * 16 + l15) * DIM +
                                    w * 128 + ks * 32 + quad * 8);

  f32x4 oac[8][4] = {};

  const int srow = tid >> 3;
  const int c0   = (tid & 7) * 4;
  const int qg   = q0 + srow;

  for (int it = 0; it < nhalf; ++it) {
    const int j0 = jbase + it * 32;
    // ---- partial QK^T over this wave's 128-d slice (Q pre-scaled) ----
    f32x4 sac[4][2] = {};
#pragma unroll
    for (int ks = 0; ks < 4; ++ks) {
      const size_t koff = (size_t)(b * SEQ + j0 + l15) * DIM + w * 128 + ks * 32 + quad * 8;
      bf16x8 kf0 = *(const bf16x8*)(Kg + koff);
      bf16x8 kf1 = *(const bf16x8*)(Kg + koff + (size_t)16 * DIM);
#pragma unroll
      for (int mq = 0; mq < 4; ++mq) {
        sac[mq][0] = __builtin_amdgcn_mfma_f32_16x16x32_bf16(qf[mq][ks], kf0, sac[mq][0], 0, 0, 0);
        sac[mq][1] = __builtin_amdgcn_mfma_f32_16x16x32_bf16(qf[mq][ks], kf1, sac[mq][1], 0, 0, 0);
      }
    }
#pragma unroll
    for (int mq = 0; mq < 4; ++mq)
#pragma unroll
      for (int n = 0; n < 2; ++n)
#pragma unroll
        for (int r = 0; r < 4; ++r)
          Sp[w][mq * 16 + quad * 4 + r][n * 16 + l15] = sac[mq][n][r];

    // ---- V prefetch: stays in flight across b1 + softmax ----
    bf16x8 vf[8];
    const unsigned short* vb = Vtg + ((size_t)b * DIM + w * 128) * SEQ + j0;
#pragma unroll
    for (int md = 0; md < 8; ++md)
      vf[md] = *(const bf16x8*)(vb + (size_t)(md * 16 + l15) * SEQ + quad * 8);

    barrier_lds();

    // ---- online softmax ----
    {
      float s[4];
#pragma unroll
      for (int i = 0; i < 4; ++i) {
        float acc = 0.f;
#pragma unroll
        for (int wv = 0; wv < 8; ++wv) acc += Sp[wv][srow][c0 + i];
        s[i] = (j0 + c0 + i > qg) ? -__builtin_inff() : acc;
      }
      float mx = fmaxf(fmaxf(s[0], s[1]), fmaxf(s[2], s[3]));
#pragma unroll
      for (int off = 1; off < 8; off <<= 1) mx = fmaxf(mx, __shfl_xor(mx, off, 8));
      const float mold = mst[srow];
      const float mnew = fmaxf(mold, mx);   // finite always (sentinel)
      const float al   = __expf(mold - mnew);
      float pv[4];
#pragma unroll
      for (int i = 0; i < 4; ++i) pv[i] = __expf(s[i] - mnew);
      u16x4 pb;
#pragma unroll
      for (int i = 0; i < 4; ++i) pb[i] = f2bf(pv[i]);
      *(u16x4*)&Pl[srow][c0] = pb;
      float sm = (pv[0] + pv[1]) + (pv[2] + pv[3]);
#pragma unroll
      for (int off = 1; off < 8; off <<= 1) sm += __shfl_xor(sm, off, 8);
      if ((tid & 7) == 0) {
        lst[srow] = lst[srow] * al + sm;
        mst[srow] = mnew;
        alf[srow] = al;
      }
    }
    barrier_lds();

    // ---- rescale O when some alpha != 1 ----
    const float a0 = alf[l15], a1 = alf[16 + l15], a2 = alf[32 + l15], a3 = alf[48 + l15];
    if (__ballot((a0 != 1.f) | (a1 != 1.f) | (a2 != 1.f) | (a3 != 1.f))) {
#pragma unroll
      for (int md = 0; md < 8; ++md)
#pragma unroll
        for (int r = 0; r < 4; ++r) {
          oac[md][0][r] *= a0; oac[md][1][r] *= a1;
          oac[md][2][r] *= a2; oac[md][3][r] *= a3;
        }
    }

    // ---- PV: O^T += V^T * P^T ----
    bf16x8 pf[4];
#pragma unroll
    for (int nq = 0; nq < 4; ++nq)
      pf[nq] = *(const bf16x8*)&Pl[nq * 16 + l15][quad * 8];
#pragma unroll
    for (int md = 0; md < 8; ++md)
#pragma unroll
      for (int nq = 0; nq < 4; ++nq)
        oac[md][nq] = __builtin_amdgcn_mfma_f32_16x16x32_bf16(vf[md], pf[nq], oac[md][nq], 0, 0, 0);
  }

  // ---- epilogue: write partial (unnormalized) + stats ----
  if (tid < 64) {
    const int r = b * SEQ + q0 + tid;
    St[h * MTOT + r]       = mst[tid];
    St[(2 + h) * MTOT + r] = lst[tid];
  }
#pragma unroll
  for (int md = 0; md < 8; ++md)
#pragma unroll
    for (int nq = 0; nq < 4; ++nq) {
      const int qq = q0 + nq * 16 + l15;
      const int d  = w * 128 + md * 16 + quad * 4;
      const size_t ro = (size_t)(b * SEQ + qq) * DIM + d;
      if (h == 0) {
        *(f32x4*)(outp + ro) = oac[md][nq];
      } else {
        u16x4 v4;
#pragma unroll
        for (int r = 0; r < 4; ++r) v4[r] = f2bf(oac[md][nq][r]);
        *(u16x4*)(O1 + ro) = v4;
      }
    }
}

// ---------------- merge the two key-half partials ----------------
__global__ __launch_bounds__(256) void combine(
    float* __restrict__ out, const unsigned short* __restrict__ O1,
    const float* __restrict__ St)
{
  const int r = blockIdx.x;
  const int d = threadIdx.x * 4;
  const float m0 = St[r],            m1 = St[MTOT + r];
  const float l0 = St[2 * MTOT + r], l1 = St[3 * MTOT + r];
  const float M  = fmaxf(m0, m1);
  const float w0 = __expf(m0 - M), w1 = __expf(m1 - M);
  const float inv = 1.0f / (w0 * l0 + w1 * l1);
  f32x4 o0 = *(const f32x4*)(out + (size_t)r * DIM + d);
  u16x4 o1 = *(const u16x4*)(O1 + (size_t)r * DIM + d);
  f32x4 res;
#pragma unroll
  for (int i = 0; i < 4; ++i) {
    union { unsigned u; float f; } c; c.u = ((unsigned)o1[i]) << 16;
    res[i] = (w0 * o0[i] + w1 * c.f) * inv;
  }
  *(f32x4*)(out + (size_t)r * DIM + d) = res;
}

extern "C" void kernel_launch(void* const* d_in, const int* in_sizes, int n_in,
                              void* d_out, int out_size, void* d_ws, size_t ws_size,
                              hipStream_t stream) {
  const float* x  = (const float*)d_in[0];
  const float* Wq = (const float*)d_in[1];
  const float* Wk = (const float*)d_in[2];
  const float* Wv = (const float*)d_in[3];
  float* out = (float*)d_out;

  // ws layout (134.25 MB):
  //   [0,32MB):    xb (bf16 x)        -> later overlaid by O1 (h=1 partial)
  //   [32,38MB):   Wb (bf16 Wq|Wk|Wv) -> later overlaid by St (m/l stats)
  //   [38,70MB):   Q bf16   [70,102MB): K bf16   [102,134MB): Vt bf16
  char* wsb = (char*)d_ws;
  unsigned short* xb = (unsigned short*)wsb;
  unsigned short* Wb = (unsigned short*)(wsb + (32u << 20));
  unsigned short* Qb = (unsigned short*)(wsb + (38u << 20));
  unsigned short* O1 = xb;
  float*          St = (float*)(wsb + (32u << 20));

  conv_bf16<<<8192, 256, 0, stream>>>(x,  xb, 2097152, 1.0f);
  conv_bf16<<<512,  256, 0, stream>>>(Wq, Wb,           131072, 0.03125f); // fold 1/sqrt(D)
  conv_bf16<<<512,  256, 0, stream>>>(Wk, Wb + 1048576, 131072, 1.0f);
  conv_bf16<<<512,  256, 0, stream>>>(Wv, Wb + 2097152, 131072, 1.0f);

  qkv_gemm2<<<dim3(8, 128, 3), 256, 0, stream>>>(xb, Wb, Qb);

  const size_t n = (size_t)MTOT * DIM;
  attn3<<<512, 512, 0, stream>>>(Qb, Qb + n, Qb + 2 * n, out, O1, St);
  combine<<<16384, 256, 0, stream>>>(out, O1, St);
}